// Round 8
// baseline (1174.248 us; speedup 1.0000x reference)
//
#include <hip/hip_runtime.h>

#define B_LEN 32
#define C_LEN 512
#define L_LEN 4096
#define H_LEN 8
#define WIN 9
#define PADW 4

#define K1_NS 8
#define K1_CPER (C_LEN / K1_NS) // 64
#define WPAD 12                 // per-(c,h) padded tap stride
#define WROW (H_LEN * WPAD)     // 96 floats per channel

// ---------------- Kernel 0: repack W [H][C][9] -> Wp [C][H][12] (pad 0) ------
__global__ __launch_bounds__(256) void repack_w(
    const float* __restrict__ W, float* __restrict__ Wp)
{
  const int i = blockIdx.x * 256 + threadIdx.x; // over C*96 = 49152
  if (i >= C_LEN * WROW) return;
  const int w = i % WPAD;
  const int h = (i / WPAD) % H_LEN;
  const int c = i / WROW;
  Wp[i] = (w < WIN) ? W[((size_t)h * C_LEN + c) * WIN + w] : 0.f;
}

// ---------------- Kernel 1: conv partial, manual register pipeline ----------
// grid (L/1024, B, K1_NS) = 1024 blocks (4/CU), block 256, no compute barriers.
// Thread t owns l = bx*1024+4t .. +3. Per channel-group of 2, the NEXT group's
// 6 float4 x-windows are loaded into named registers BEFORE the current
// group's 576 FMAs, so the vmcnt wait lands after the FMA block (latency
// hidden). W is staged once into LDS (24.6 KB) -> uniform broadcast ds_reads.
__global__ __launch_bounds__(256, 4) void conv_direct(
    const float* __restrict__ x, const float* __restrict__ Wp,
    float* __restrict__ part)
{
  __shared__ float wl[K1_CPER * WROW]; // 24.6 KB
  const int t = threadIdx.x;
  const int li = blockIdx.x * 1024 + 4 * t;
  const int b = blockIdx.y;
  const int cbase = blockIdx.z * K1_CPER;
  // base includes cbase (R7 bug: it was missing -> wrong channels convolved)
  const float* xb = x + (size_t)b * C_LEN * L_LEN + (size_t)cbase * L_LEN + li;

  // stage W chunk (coalesced float4), one barrier total
  for (int i = t; i < K1_CPER * WROW / 4; i += 256)
    *reinterpret_cast<float4*>(&wl[4 * i]) =
        *reinterpret_cast<const float4*>(&Wp[(size_t)cbase * WROW + 4 * i]);
  __syncthreads();

  float acc[H_LEN][4];
#pragma unroll
  for (int h = 0; h < H_LEN; ++h)
#pragma unroll
    for (int j = 0; j < 4; ++j) acc[h][j] = 0.f;

  const bool lok = (li >= 4);        // left float4 fully in-bounds
  const bool rok = (li + 7 < L_LEN); // right float4 fully in-bounds
  const int loff = lok ? -4 : 0;     // clamped (safe) addresses, value-masked later
  const int roff = rok ? 4 : 0;
  const float4 z4 = make_float4(0.f, 0.f, 0.f, 0.f);

  float4 cur[2][3], nxt[2][3];
  auto LD = [&](int c, float4 (&v)[3]) { // c = LOCAL channel 0..63
    const float* xc = xb + (size_t)c * L_LEN;
    v[0] = *reinterpret_cast<const float4*>(xc + loff);
    v[1] = *reinterpret_cast<const float4*>(xc);
    v[2] = *reinterpret_cast<const float4*>(xc + roff);
  };

  LD(0, cur[0]);
  LD(1, cur[1]);

#pragma unroll 2
  for (int g = 0; g < K1_CPER / 2; ++g) {
    if (g + 1 < K1_CPER / 2) { // prefetch next group into named regs
      LD(2 * g + 2, nxt[0]);
      LD(2 * g + 3, nxt[1]);
    }
#pragma unroll
    for (int u = 0; u < 2; ++u) {
      const int c = 2 * g + u;
      const float4 a0 = lok ? cur[u][0] : z4;
      const float4 a1 = cur[u][1];
      const float4 a2 = rok ? cur[u][2] : z4;
      float xv[12];
      xv[0] = a0.x; xv[1] = a0.y; xv[2]  = a0.z; xv[3]  = a0.w;
      xv[4] = a1.x; xv[5] = a1.y; xv[6]  = a1.z; xv[7]  = a1.w;
      xv[8] = a2.x; xv[9] = a2.y; xv[10] = a2.z; xv[11] = a2.w;
      const float* wc = &wl[c * WROW];
#pragma unroll
      for (int h = 0; h < H_LEN; ++h) {
        const float4 w0 = *reinterpret_cast<const float4*>(wc + h * WPAD);
        const float4 w1 = *reinterpret_cast<const float4*>(wc + h * WPAD + 4);
        const float  w8 = wc[h * WPAD + 8];
#pragma unroll
        for (int j = 0; j < 4; ++j) {
          float s = acc[h][j];
          s = fmaf(xv[j + 0], w0.x, s);
          s = fmaf(xv[j + 1], w0.y, s);
          s = fmaf(xv[j + 2], w0.z, s);
          s = fmaf(xv[j + 3], w0.w, s);
          s = fmaf(xv[j + 4], w1.x, s);
          s = fmaf(xv[j + 5], w1.y, s);
          s = fmaf(xv[j + 6], w1.z, s);
          s = fmaf(xv[j + 7], w1.w, s);
          s = fmaf(xv[j + 8], w8, s);
          acc[h][j] = s;
        }
      }
    }
#pragma unroll
    for (int u = 0; u < 2; ++u)
#pragma unroll
      for (int q = 0; q < 3; ++q) cur[u][q] = nxt[u][q];
  }

  float* dst = part + ((size_t)blockIdx.z * B_LEN * H_LEN + (size_t)b * H_LEN) * L_LEN + li;
#pragma unroll
  for (int h = 0; h < H_LEN; ++h) {
    float4 v;
    v.x = acc[h][0]; v.y = acc[h][1]; v.z = acc[h][2]; v.w = acc[h][3];
    *reinterpret_cast<float4*>(dst + (size_t)h * L_LEN) = v;
  }
}

// ---------------- Kernel 2: sum partials + softmax over L ----------------
__global__ __launch_bounds__(256) void softmax_rows(
    const float* __restrict__ part, float* __restrict__ focus)
{
  __shared__ float red[256];
  const int r = blockIdx.x; // b*H + h
  const int t = threadIdx.x;
  const size_t PART = (size_t)B_LEN * H_LEN * L_LEN;
  float v[16];
#pragma unroll
  for (int k = 0; k < 4; ++k) {
    const int i4 = (t + 256 * k) * 4;
    float4 a = *reinterpret_cast<const float4*>(&part[(size_t)r * L_LEN + i4]);
    v[4 * k + 0] = a.x; v[4 * k + 1] = a.y; v[4 * k + 2] = a.z; v[4 * k + 3] = a.w;
  }
  for (int s = 1; s < K1_NS; ++s) {
#pragma unroll
    for (int k = 0; k < 4; ++k) {
      const int i4 = (t + 256 * k) * 4;
      float4 a = *reinterpret_cast<const float4*>(&part[(size_t)s * PART + (size_t)r * L_LEN + i4]);
      v[4 * k + 0] += a.x; v[4 * k + 1] += a.y; v[4 * k + 2] += a.z; v[4 * k + 3] += a.w;
    }
  }
  // bias b[h] is constant along L -> softmax-invariant -> skipped
  float m = v[0];
#pragma unroll
  for (int k = 1; k < 16; ++k) m = fmaxf(m, v[k]);
  red[t] = m;
  __syncthreads();
  for (int s = 128; s > 0; s >>= 1) {
    if (t < s) red[t] = fmaxf(red[t], red[t + s]);
    __syncthreads();
  }
  m = red[0];
  __syncthreads();
  float sum = 0.f;
#pragma unroll
  for (int k = 0; k < 16; ++k) { v[k] = __expf(v[k] - m); sum += v[k]; }
  red[t] = sum;
  __syncthreads();
  for (int s = 128; s > 0; s >>= 1) {
    if (t < s) red[t] += red[t + s];
    __syncthreads();
  }
  const float inv = 1.f / red[0];
#pragma unroll
  for (int k = 0; k < 4; ++k) {
    const int i4 = (t + 256 * k) * 4;
    float4 a;
    a.x = v[4 * k + 0] * inv; a.y = v[4 * k + 1] * inv;
    a.z = v[4 * k + 2] * inv; a.w = v[4 * k + 3] * inv;
    *reinterpret_cast<float4*>(&focus[(size_t)r * L_LEN + i4]) = a;
  }
}

// ---------------- Kernel 3a: partial pooled over an L-split ----------------
#define K3_ST 68
#define K3_NS 4

__global__ __launch_bounds__(256) void pool_partial(
    const float* __restrict__ x, const float* __restrict__ focus,
    float* __restrict__ pool2)
{
  __shared__ float xs[64 * K3_ST];
  const int t = threadIdx.x;
  const int cl = t & 63;
  const int p = t >> 6;                              // h-group 0..3 (wave-uniform)
  const int pu = __builtin_amdgcn_readfirstlane(p);  // force SGPR for focus addressing
  const int b = blockIdx.y;
  const int c0 = blockIdx.x * 64;
  const int lbeg = blockIdx.z * (L_LEN / K3_NS);
  const float* f0 = focus + ((size_t)b * H_LEN + pu) * L_LEN;
  const float* f1 = f0 + 4 * (size_t)L_LEN;
  const float* xb = x + (size_t)b * C_LEN * L_LEN;
  const int srow = t >> 4;
  const int scol = (t & 15) * 4;
  float acc0 = 0.f, acc1 = 0.f;

  for (int l0 = lbeg; l0 < lbeg + L_LEN / K3_NS; l0 += 64) {
    __syncthreads();
#pragma unroll
    for (int pass = 0; pass < 4; ++pass) {
      const int c = srow + pass * 16;
      float4 v = *reinterpret_cast<const float4*>(&xb[(size_t)(c0 + c) * L_LEN + l0 + scol]);
      *reinterpret_cast<float4*>(&xs[c * K3_ST + scol]) = v;
    }
    __syncthreads();
#pragma unroll
    for (int l4 = 0; l4 < 16; ++l4) {
      const float4 xv = *reinterpret_cast<const float4*>(&xs[cl * K3_ST + 4 * l4]);
      const int li = l0 + 4 * l4;
      acc0 = fmaf(xv.x, f0[li + 0], acc0);
      acc0 = fmaf(xv.y, f0[li + 1], acc0);
      acc0 = fmaf(xv.z, f0[li + 2], acc0);
      acc0 = fmaf(xv.w, f0[li + 3], acc0);
      acc1 = fmaf(xv.x, f1[li + 0], acc1);
      acc1 = fmaf(xv.y, f1[li + 1], acc1);
      acc1 = fmaf(xv.z, f1[li + 2], acc1);
      acc1 = fmaf(xv.w, f1[li + 3], acc1);
    }
  }
  // partial pooled, layout [ls][b][c][h]
  float* dst = pool2 + (((size_t)blockIdx.z * B_LEN + b) * C_LEN + c0 + cl) * H_LEN;
  dst[p] = acc0;
  dst[p + 4] = acc1;
}

// ---------------- Kernel 3b: sum L-splits, max over heads ----------------
__global__ __launch_bounds__(256) void pool_reduce(
    const float* __restrict__ pool2, float* __restrict__ out)
{
  const int i = blockIdx.x * 256 + threadIdx.x; // over B*C
  float s[H_LEN];
#pragma unroll
  for (int h = 0; h < H_LEN; ++h) s[h] = 0.f;
  for (int ls = 0; ls < K3_NS; ++ls) {
    const float* src = pool2 + ((size_t)ls * B_LEN * C_LEN + i) * H_LEN;
    float4 a = *reinterpret_cast<const float4*>(src);
    float4 b4 = *reinterpret_cast<const float4*>(src + 4);
    s[0] += a.x; s[1] += a.y; s[2] += a.z; s[3] += a.w;
    s[4] += b4.x; s[5] += b4.y; s[6] += b4.z; s[7] += b4.w;
  }
  float m = s[0];
#pragma unroll
  for (int h = 1; h < H_LEN; ++h) m = fmaxf(m, s[h]);
  out[i] = m;
}

extern "C" void kernel_launch(void* const* d_in, const int* in_sizes, int n_in,
                              void* d_out, int out_size, void* d_ws, size_t ws_size,
                              hipStream_t stream)
{
  const float* x = (const float*)d_in[0];
  const float* W = (const float*)d_in[1];
  // d_in[2] = bias: constant along L, softmax-invariant -> no effect on output.
  float* out = (float*)d_out;
  float* ws = (float*)d_ws;

  const size_t PART = (size_t)B_LEN * H_LEN * L_LEN;            // 1M floats
  const size_t POOL2N = (size_t)K3_NS * B_LEN * C_LEN * H_LEN;  // 512K floats

  float* part = ws;                          // 8 * 4 MB
  float* focus = ws + (size_t)K1_NS * PART;  // 4 MB
  float* pool2 = focus + PART;               // 2 MB
  float* Wp = pool2 + POOL2N;                // 192 KB

  hipLaunchKernelGGL(repack_w, dim3((C_LEN * WROW + 255) / 256), dim3(256), 0,
                     stream, W, Wp);
  hipLaunchKernelGGL(conv_direct, dim3(L_LEN / 1024, B_LEN, K1_NS), dim3(256), 0,
                     stream, x, Wp, part);
  hipLaunchKernelGGL(softmax_rows, dim3(B_LEN * H_LEN), dim3(256), 0,
                     stream, part, focus);
  hipLaunchKernelGGL(pool_partial, dim3(C_LEN / 64, B_LEN, K3_NS), dim3(256), 0,
                     stream, x, focus, pool2);
  hipLaunchKernelGGL(pool_reduce, dim3((B_LEN * C_LEN) / 256), dim3(256), 0,
                     stream, pool2, out);
}

// Round 9
// 139.859 us; speedup vs baseline: 8.3959x; 8.3959x over previous
//
#include <hip/hip_runtime.h>

#define B_LEN 32
#define C_LEN 512
#define L_LEN 4096
#define H_LEN 8
#define WIN 9

typedef __attribute__((ext_vector_type(8))) short short8v;  // 8 bf16 = 4 VGPR (guide §3)
typedef __attribute__((ext_vector_type(4))) short short4v;  // 4 bf16 = 8B
typedef __attribute__((ext_vector_type(4))) float float4v;

// fp32 -> bf16 RNE (normal inputs; avoids header dependency surprises)
__device__ __forceinline__ short f2bf(float f) {
  unsigned u = __float_as_uint(f);
  unsigned r = (u + 0x7fffu + ((u >> 16) & 1u)) >> 16;
  return (short)r;
}

// swizzled byte offset in the xt tile: row in [0,264), colbyte in [0,128)
// XOR key ((row>>1)&7)<<4 keeps 16B alignment (b128 reads) and spreads the
// 16-consecutive-row frag reads evenly over all 32 banks.
__device__ __forceinline__ int xoff(int row, int colbyte) {
  return row * 128 + (colbyte ^ (((row >> 1) & 7) << 4));
}

// ------------- Kernel 0: repack W [H][C][9] -> Wt bf16 [9][16][512] ----------
// h rows 8..15 are ZERO so MFMA A-rows 8-15 produce zeros (no masking needed).
__global__ __launch_bounds__(256) void repack_w_bf16(
    const float* __restrict__ W, short* __restrict__ Wt)
{
  const int i = blockIdx.x * 256 + threadIdx.x; // over 9*16*512 = 73728
  if (i >= WIN * 16 * C_LEN) return;
  const int c = i & 511;
  const int h = (i >> 9) & 15;
  const int w = i / (16 * C_LEN);
  const float v = (h < H_LEN) ? W[((size_t)h * C_LEN + c) * WIN + w] : 0.f;
  Wt[i] = f2bf(v);
}

// ------------- Kernel 1: conv via bf16 MFMA ----------------------------------
// grid (L/256=16, B=32) = 512 blocks (2/CU), block 256 (4 waves).
// Each wave owns 64 l (4 subtiles of 16). LDS: double-buffered swizzled bf16
// tile xt[264 rows = 256 l + 8 halo][64 c]. K-loop: 8 c-chunks x 9 w x 2 kc.
// A-frag = Wt (global, 16B/lane, prefetched 1 w ahead); B-frag = xt ds_read_b128.
// k-slot mapping for BOTH frags: c = cb + 8*(lane>>4) + elem (permutation-
// invariant trick). D (m89-verified): col=lane&15=l-offset, row=(lane>>4)*4+reg=h.
__global__ __launch_bounds__(256) void conv_mfma(
    const float* __restrict__ x, const short* __restrict__ Wt,
    float* __restrict__ part)
{
  __shared__ short xt[2][264 * 64]; // 2 x 33792 B = 66 KB
  const int t = threadIdx.x;
  const int lane = t & 63;
  const int wid = t >> 6;
  const int j15 = lane & 15;
  const int g = lane >> 4;
  const int g16 = g * 16;
  const int b = blockIdx.y;
  const int l0b = blockIdx.x * 256;
  const float* xb = x + (size_t)b * C_LEN * L_LEN;
  const int wl0 = wid * 64;

  // stage c-chunk cc2 (64 channels x 264 l) as bf16 transposed+swizzled
  auto STAGE = [&](int buf, int cc2) {
    char* bb = (char*)&xt[buf][0];
    const int lq = t & 63;  // l-quad: rows 4lq..4lq+3 (+4 halo offset)
    const int cg = t >> 6;  // wave-uniform c-subgroup
#pragma unroll
    for (int p = 0; p < 4; ++p) {
      const int cl = p * 16 + cg * 4;
      const float* src = xb + (size_t)(cc2 * 64 + cl) * L_LEN + (l0b + 4 * lq);
      const float4 v0 = *reinterpret_cast<const float4*>(src);
      const float4 v1 = *reinterpret_cast<const float4*>(src + L_LEN);
      const float4 v2 = *reinterpret_cast<const float4*>(src + 2 * L_LEN);
      const float4 v3 = *reinterpret_cast<const float4*>(src + 3 * L_LEN);
      const int colb = cl * 2;
      const short4v r0 = { f2bf(v0.x), f2bf(v1.x), f2bf(v2.x), f2bf(v3.x) };
      const short4v r1 = { f2bf(v0.y), f2bf(v1.y), f2bf(v2.y), f2bf(v3.y) };
      const short4v r2 = { f2bf(v0.z), f2bf(v1.z), f2bf(v2.z), f2bf(v3.z) };
      const short4v r3 = { f2bf(v0.w), f2bf(v1.w), f2bf(v2.w), f2bf(v3.w) };
      *(short4v*)(bb + xoff(4 * lq + 4, colb)) = r0;
      *(short4v*)(bb + xoff(4 * lq + 5, colb)) = r1;
      *(short4v*)(bb + xoff(4 * lq + 6, colb)) = r2;
      *(short4v*)(bb + xoff(4 * lq + 7, colb)) = r3;
    }
    if (t < 32) { // halo: rows 0-3 (l0b-4..-1) and 260-263 (l0b+256..259)
      const int c4 = t & 15;
      const int side = t >> 4;
      const int cl = c4 * 4;
      const int gl = side ? (l0b + 256) : (l0b - 4);
      const bool ok = side ? (l0b + 256 < L_LEN) : (l0b > 0);
      float4 v0 = make_float4(0.f, 0.f, 0.f, 0.f), v1 = v0, v2 = v0, v3 = v0;
      if (ok) {
        const float* src = xb + (size_t)(cc2 * 64 + cl) * L_LEN + gl;
        v0 = *reinterpret_cast<const float4*>(src);
        v1 = *reinterpret_cast<const float4*>(src + L_LEN);
        v2 = *reinterpret_cast<const float4*>(src + 2 * L_LEN);
        v3 = *reinterpret_cast<const float4*>(src + 3 * L_LEN);
      }
      const int colb = cl * 2;
      const int r = side ? 260 : 0;
      const short4v r0 = { f2bf(v0.x), f2bf(v1.x), f2bf(v2.x), f2bf(v3.x) };
      const short4v r1 = { f2bf(v0.y), f2bf(v1.y), f2bf(v2.y), f2bf(v3.y) };
      const short4v r2 = { f2bf(v0.z), f2bf(v1.z), f2bf(v2.z), f2bf(v3.z) };
      const short4v r3 = { f2bf(v0.w), f2bf(v1.w), f2bf(v2.w), f2bf(v3.w) };
      *(short4v*)(bb + xoff(r + 0, colb)) = r0;
      *(short4v*)(bb + xoff(r + 1, colb)) = r1;
      *(short4v*)(bb + xoff(r + 2, colb)) = r2;
      *(short4v*)(bb + xoff(r + 3, colb)) = r3;
    }
  };

  float4v acc0 = {0.f, 0.f, 0.f, 0.f};
  float4v acc1 = acc0, acc2 = acc0, acc3 = acc0;
  const int wlane = j15 * C_LEN + 8 * g; // per-lane Wt offset (shorts)

  STAGE(0, 0);
  __syncthreads();

  for (int cc = 0; cc < 8; ++cc) {
    if (cc < 7) STAGE((cc + 1) & 1, cc + 1); // async-ish prefetch into other buf
    const char* base = (const char*)&xt[cc & 1][0];
    const short* Wc = Wt + cc * 64 + wlane; // + w*8192 + kc*32
    short8v wf0 = *(const short8v*)(Wc);
    short8v wf1 = *(const short8v*)(Wc + 32);
#pragma unroll
    for (int w = 0; w < WIN; ++w) {
      short8v wn0 = wf0, wn1 = wf1;
      if (w + 1 < WIN) { // prefetch next w's W-frags (hides L2 latency)
        wn0 = *(const short8v*)(Wc + (w + 1) * (16 * C_LEN));
        wn1 = *(const short8v*)(Wc + (w + 1) * (16 * C_LEN) + 32);
      }
      const int rbase = wl0 + j15 + w;
#define MSTEP(SUB, ACC)                                                        \
      {                                                                        \
        short8v xfa = *(const short8v*)(base + xoff(rbase + SUB * 16, g16));   \
        ACC = __builtin_amdgcn_mfma_f32_16x16x32_bf16(wf0, xfa, ACC, 0, 0, 0); \
        short8v xfb = *(const short8v*)(base + xoff(rbase + SUB * 16, 64 + g16)); \
        ACC = __builtin_amdgcn_mfma_f32_16x16x32_bf16(wf1, xfb, ACC, 0, 0, 0); \
      }
      MSTEP(0, acc0) MSTEP(1, acc1) MSTEP(2, acc2) MSTEP(3, acc3)
#undef MSTEP
      wf0 = wn0; wf1 = wn1;
    }
    __syncthreads();
  }

  // D: col = lane&15 = l-offset, row = (lane>>4)*4 + reg = h (valid for g<2)
  if (lane < 32) {
    float* d = part + ((size_t)b * H_LEN + 4 * g) * L_LEN + (l0b + wl0 + j15);
#pragma unroll
    for (int r = 0; r < 4; ++r) {
      d[(size_t)r * L_LEN +  0] = acc0[r];
      d[(size_t)r * L_LEN + 16] = acc1[r];
      d[(size_t)r * L_LEN + 32] = acc2[r];
      d[(size_t)r * L_LEN + 48] = acc3[r];
    }
  }
}

// ------------- Kernel 2: softmax over L (logits complete, nsplit gone) -------
__global__ __launch_bounds__(256) void softmax_rows(
    const float* __restrict__ part, float* __restrict__ focus)
{
  __shared__ float red[256];
  const int r = blockIdx.x; // b*H + h
  const int t = threadIdx.x;
  float v[16];
#pragma unroll
  for (int k = 0; k < 4; ++k) {
    const int i4 = (t + 256 * k) * 4;
    float4 a = *reinterpret_cast<const float4*>(&part[(size_t)r * L_LEN + i4]);
    v[4 * k + 0] = a.x; v[4 * k + 1] = a.y; v[4 * k + 2] = a.z; v[4 * k + 3] = a.w;
  }
  // bias b[h] is constant along L -> softmax-invariant -> skipped
  float m = v[0];
#pragma unroll
  for (int k = 1; k < 16; ++k) m = fmaxf(m, v[k]);
  red[t] = m;
  __syncthreads();
  for (int s = 128; s > 0; s >>= 1) {
    if (t < s) red[t] = fmaxf(red[t], red[t + s]);
    __syncthreads();
  }
  m = red[0];
  __syncthreads();
  float sum = 0.f;
#pragma unroll
  for (int k = 0; k < 16; ++k) { v[k] = __expf(v[k] - m); sum += v[k]; }
  red[t] = sum;
  __syncthreads();
  for (int s = 128; s > 0; s >>= 1) {
    if (t < s) red[t] += red[t + s];
    __syncthreads();
  }
  const float inv = 1.f / red[0];
#pragma unroll
  for (int k = 0; k < 4; ++k) {
    const int i4 = (t + 256 * k) * 4;
    float4 a;
    a.x = v[4 * k + 0] * inv; a.y = v[4 * k + 1] * inv;
    a.z = v[4 * k + 2] * inv; a.w = v[4 * k + 3] * inv;
    *reinterpret_cast<float4*>(&focus[(size_t)r * L_LEN + i4]) = a;
  }
}

// ------------- Kernel 3a: partial pooled over an L-split ---------------------
#define K3_ST 68
#define K3_NS 4

__global__ __launch_bounds__(256) void pool_partial(
    const float* __restrict__ x, const float* __restrict__ focus,
    float* __restrict__ pool2)
{
  __shared__ float xs[64 * K3_ST];
  const int t = threadIdx.x;
  const int cl = t & 63;
  const int p = t >> 6;
  const int pu = __builtin_amdgcn_readfirstlane(p);
  const int b = blockIdx.y;
  const int c0 = blockIdx.x * 64;
  const int lbeg = blockIdx.z * (L_LEN / K3_NS);
  const float* f0 = focus + ((size_t)b * H_LEN + pu) * L_LEN;
  const float* f1 = f0 + 4 * (size_t)L_LEN;
  const float* xb = x + (size_t)b * C_LEN * L_LEN;
  const int srow = t >> 4;
  const int scol = (t & 15) * 4;
  float acc0 = 0.f, acc1 = 0.f;

  for (int l0 = lbeg; l0 < lbeg + L_LEN / K3_NS; l0 += 64) {
    __syncthreads();
#pragma unroll
    for (int pass = 0; pass < 4; ++pass) {
      const int c = srow + pass * 16;
      float4 v = *reinterpret_cast<const float4*>(&xb[(size_t)(c0 + c) * L_LEN + l0 + scol]);
      *reinterpret_cast<float4*>(&xs[c * K3_ST + scol]) = v;
    }
    __syncthreads();
#pragma unroll
    for (int l4 = 0; l4 < 16; ++l4) {
      const float4 xv = *reinterpret_cast<const float4*>(&xs[cl * K3_ST + 4 * l4]);
      const int li = l0 + 4 * l4;
      acc0 = fmaf(xv.x, f0[li + 0], acc0);
      acc0 = fmaf(xv.y, f0[li + 1], acc0);
      acc0 = fmaf(xv.z, f0[li + 2], acc0);
      acc0 = fmaf(xv.w, f0[li + 3], acc0);
      acc1 = fmaf(xv.x, f1[li + 0], acc1);
      acc1 = fmaf(xv.y, f1[li + 1], acc1);
      acc1 = fmaf(xv.z, f1[li + 2], acc1);
      acc1 = fmaf(xv.w, f1[li + 3], acc1);
    }
  }
  float* dst = pool2 + (((size_t)blockIdx.z * B_LEN + b) * C_LEN + c0 + cl) * H_LEN;
  dst[p] = acc0;
  dst[p + 4] = acc1;
}

// ------------- Kernel 3b: sum L-splits, max over heads ------------------------
__global__ __launch_bounds__(256) void pool_reduce(
    const float* __restrict__ pool2, float* __restrict__ out)
{
  const int i = blockIdx.x * 256 + threadIdx.x; // over B*C
  float s[H_LEN];
#pragma unroll
  for (int h = 0; h < H_LEN; ++h) s[h] = 0.f;
  for (int ls = 0; ls < K3_NS; ++ls) {
    const float* src = pool2 + ((size_t)ls * B_LEN * C_LEN + i) * H_LEN;
    float4 a = *reinterpret_cast<const float4*>(src);
    float4 b4 = *reinterpret_cast<const float4*>(src + 4);
    s[0] += a.x; s[1] += a.y; s[2] += a.z; s[3] += a.w;
    s[4] += b4.x; s[5] += b4.y; s[6] += b4.z; s[7] += b4.w;
  }
  float m = s[0];
#pragma unroll
  for (int h = 1; h < H_LEN; ++h) m = fmaxf(m, s[h]);
  out[i] = m;
}

extern "C" void kernel_launch(void* const* d_in, const int* in_sizes, int n_in,
                              void* d_out, int out_size, void* d_ws, size_t ws_size,
                              hipStream_t stream)
{
  const float* x = (const float*)d_in[0];
  const float* W = (const float*)d_in[1];
  // d_in[2] = bias: constant along L, softmax-invariant -> no effect on output.
  float* out = (float*)d_out;
  float* ws = (float*)d_ws;

  const size_t PART = (size_t)B_LEN * H_LEN * L_LEN;            // 1M floats
  const size_t POOL2N = (size_t)K3_NS * B_LEN * C_LEN * H_LEN;  // 512K floats

  float* part = ws;                      // 4 MB (full logits, no splits)
  float* focus = ws + PART;              // 4 MB
  float* pool2 = focus + PART;           // 2 MB
  short* Wt = (short*)(pool2 + POOL2N);  // 9*16*512 bf16 = 147 KB

  hipLaunchKernelGGL(repack_w_bf16, dim3((WIN * 16 * C_LEN + 255) / 256), dim3(256), 0,
                     stream, W, Wt);
  hipLaunchKernelGGL(conv_mfma, dim3(L_LEN / 256, B_LEN), dim3(256), 0,
                     stream, x, Wt, part);
  hipLaunchKernelGGL(softmax_rows, dim3(B_LEN * H_LEN), dim3(256), 0,
                     stream, part, focus);
  hipLaunchKernelGGL(pool_partial, dim3(C_LEN / 64, B_LEN, K3_NS), dim3(256), 0,
                     stream, x, focus, pool2);
  hipLaunchKernelGGL(pool_reduce, dim3((B_LEN * C_LEN) / 256), dim3(256), 0,
                     stream, pool2, out);
}